// Round 4
// baseline (33.795 us; speedup 1.0000x reference)
//
#include <hip/hip_runtime.h>

// op 0: fmod(a,b) * W_mod ; op 1: gcd(int(a),int(b)) * W_gcd ; else 0.
// a,b integer-valued floats in [1, 1e6) -> exact in fp32.
//
// mod step: q = floor(fma(x, rcp(y), -0.5)) is within +/-0.19 of x/y - 0.5
// (rcp <=1 ulp, x < 2^20), so q in {k-1, k}; r = fma(-q, y, x) is an exact
// integer in [0, 2y). One conditional subtract gives the exact mod (phase A).
//
// gcd (phase B) uses CENTERED remainders computed directly from r in [0,2y):
//   c = min3(r, |r - y|, 2y - r)   (= distance from r to nearest multiple of y)
// gcd(y, c) == gcd(y, r) since c == +/-r (mod y); c <= y/2 so y at least
// halves per step -> <= ~20 steps, avg ~8.
//
// Phase B processes TWO queue items per lane in one branchless combined loop:
// two independent dependency chains (2x ILP on the serial rcp/fma chain) and
// ONE wave-max over ~128 items instead of two sequential wave-maxes over 64.
// Dead/finished items step safely: ys = max(y,1) -> r = 1, c = 0, x kept.
//
// Each WAVE owns 256 elements (4/lane); compaction uses ballot + prefix-popc
// + an SGPR running count. No atomics, no __syncthreads (same-wave LDS
// ordering is guaranteed by the in-order DS pipeline).

#define TPB 256

__device__ __forceinline__ float mod_step(float x, float y) {
    // precondition: y >= 1, x >= 0, both integer-valued, < 2^20
    float q = floorf(fmaf(x, __builtin_amdgcn_rcpf(y), -0.5f));
    float r = fmaf(-q, y, x);          // exact integer in [0, 2y)
    return (r >= y) ? r - y : r;
}

__device__ __forceinline__ void cstep(float& x, float& y) {
    // one centered-Euclid step; no-op (keeps x, y stays 0) when y == 0
    const float ys = fmaxf(y, 1.0f);
    const float q  = floorf(fmaf(x, __builtin_amdgcn_rcpf(ys), -0.5f));
    const float r  = fmaf(-q, ys, x);                    // exact, [0, 2*ys)
    const float c  = fminf(r, fminf(fabsf(r - ys), fmaf(2.0f, ys, -r)));
    x = (y > 0.0f) ? y : x;
    y = c;
}

extern "C" __global__ void __launch_bounds__(256)
nt_kernel(const float4* __restrict__ a4, const float4* __restrict__ b4,
          const int4* __restrict__ op4, const float* __restrict__ Wm,
          const float* __restrict__ Wg, float4* __restrict__ out4, int n4)
{
    __shared__ __align__(16) float res[1024];   // per-block results, 4/thread
    __shared__ float qb[1024];                  // queue: x0 = b
    __shared__ float qr[1024];                  // queue: y0 = a mod b
    __shared__ int   qs[1024];                  // queue: result slot

    const int tid   = threadIdx.x;
    const int lane  = tid & 63;
    const int wbase = (tid >> 6) << 8;          // 256 queue slots per wave

    const int i = blockIdx.x * TPB + tid;       // float4 index
    const bool valid = (i < n4);
    const float wm = Wm[0];
    const float wg = Wg[0];

    // ---- phase A: mod for everyone, wave-local gcd-task compaction ----
    int qcount = 0;
    if (valid) {
        const float4 a = a4[i];
        const float4 b = b4[i];
        const int4  op = op4[i];
        float4 o;
        #pragma unroll
        for (int j = 0; j < 4; ++j) {
            const float aj = (&a.x)[j];
            const float bj = (&b.x)[j];
            const int  opj = (&op.x)[j];
            const float r0 = mod_step(aj, bj);        // a mod b, exact
            (&o.x)[j] = (opj == 0) ? r0 * wm : 0.0f;  // op1 slots overwritten in B
            const bool need = (opj == 1);
            const unsigned long long mask = __ballot(need);
            if (need) {
                const int pos = wbase + qcount +
                    (int)__popcll(mask & ((1ull << lane) - 1ull));
                qb[pos] = bj;
                qr[pos] = r0;
                qs[pos] = tid * 4 + j;
            }
            qcount += (int)__popcll(mask);            // wave-uniform (SGPR)
        }
        ((float4*)res)[tid] = o;                      // one ds_write_b128
    }

    // ---- phase B: paired dense centered-Euclid over the wave's own queue ----
    // (no barrier: producer and consumer are the same wave)
    for (int base = 0; base < qcount; base += 128) {
        const int k1 = base + lane;
        const int k2 = base + 64 + lane;
        const bool v1 = (k1 < qcount);
        const bool v2 = (k2 < qcount);
        float x1 = 1.0f, y1 = 0.0f, x2 = 1.0f, y2 = 0.0f;
        int   s1 = 0,    s2 = 0;
        if (v1) { x1 = qb[wbase + k1]; y1 = qr[wbase + k1]; s1 = qs[wbase + k1]; }
        if (v2) { x2 = qb[wbase + k2]; y2 = qr[wbase + k2]; s2 = qs[wbase + k2]; }
        while (y1 + y2 > 0.0f) {       // both nonneg; exits when both done
            cstep(x1, y1);
            cstep(x2, y2);
        }
        if (v1) res[s1] = x1 * wg;
        if (v2) res[s2] = x2 * wg;
    }

    // ---- phase C: coalesced write-out (own wave's region only) ----
    if (valid) {
        out4[i] = ((const float4*)res)[tid];
    }
}

extern "C" void kernel_launch(void* const* d_in, const int* in_sizes, int n_in,
                              void* d_out, int out_size, void* d_ws, size_t ws_size,
                              hipStream_t stream) {
    const float* a   = (const float*)d_in[0];
    const float* b   = (const float*)d_in[1];
    const int*   op  = (const int*)d_in[2];
    const float* Wm  = (const float*)d_in[3];
    const float* Wg  = (const float*)d_in[4];
    float* out = (float*)d_out;

    const int n  = in_sizes[0];      // 8388608
    const int n4 = n >> 2;           // 2097152 float4 elements
    const int blocks = (n4 + TPB - 1) / TPB;   // 8192

    nt_kernel<<<blocks, TPB, 0, stream>>>(
        (const float4*)a, (const float4*)b, (const int4*)op, Wm, Wg,
        (float4*)out, n4);
}

// Round 5
// 28.325 us; speedup vs baseline: 1.1931x; 1.1931x over previous
//
#include <hip/hip_runtime.h>

// op 0: fmod(a,b) * W_mod ; op 1: gcd(int(a),int(b)) * W_gcd ; else 0.
// a,b integer-valued floats in [1, 1e6) -> exact in fp32.
//
// mod step (phase A, exact plain mod): q = floor(fma(x, rcp(y), -0.5)) is
// within +/-0.19 of x/y - 0.5 (rcp <=1 ulp, x < 2^20), so q in {k-1, k};
// r = fma(-q, y, x) is an exact integer in [0, 2y); one conditional subtract.
//
// gcd (phase B) uses CENTERED remainders computed via a single min3:
//   r in [0, 2y)  ->  c = min3(r, |r - y|, 2y - r)
// (= distance from r to the nearest multiple of y). gcd(y, c) == gcd(y, r)
// since c == +/-r (mod y); c <= y/2 so y at least halves per step
// -> <= ~20 steps, avg ~6-7. |r-y| is a free VOP3 input modifier and
// fminf(fminf(..)) fuses to v_min3_f32: inner loop = 7 VALU ops.
//
// ISSUE-BOUND lesson from round 4: sequential early-exit loops beat paired
// branchless ones (pairing raised total issued instructions: 2*E[max128] vs
// E[max64]+E[max64] iterations). Keep phase B sequential.
//
// Each WAVE owns 256 elements (4/lane); gcd tasks are compacted into a
// wave-private LDS queue via ballot + prefix-popc + SGPR running count.
// No atomics, no __syncthreads (same-wave LDS ordering is guaranteed by the
// in-order DS pipeline). Queue payload (b, r0) packed as float2 -> b64 DS ops.

#define TPB 256

__device__ __forceinline__ float mod_step(float x, float y) {
    // precondition: y >= 1, x >= 0, both integer-valued, < 2^20
    float q = floorf(fmaf(x, __builtin_amdgcn_rcpf(y), -0.5f));
    float r = fmaf(-q, y, x);          // exact integer in [0, 2y)
    return (r >= y) ? r - y : r;
}

extern "C" __global__ void __launch_bounds__(256)
nt_kernel(const float4* __restrict__ a4, const float4* __restrict__ b4,
          const int4* __restrict__ op4, const float* __restrict__ Wm,
          const float* __restrict__ Wg, float4* __restrict__ out4, int n4)
{
    __shared__ __align__(16) float  res[1024];  // per-block results, 4/thread
    __shared__ __align__(8)  float2 qbr[1024];  // queue: (x0 = b, y0 = a mod b)
    __shared__ int    qs[1024];                 // queue: result slot

    const int tid   = threadIdx.x;
    const int lane  = tid & 63;
    const int wbase = (tid >> 6) << 8;          // 256 queue slots per wave

    const int i = blockIdx.x * TPB + tid;       // float4 index
    const bool valid = (i < n4);
    const float wm = Wm[0];
    const float wg = Wg[0];

    // ---- phase A: mod for everyone, wave-local gcd-task compaction ----
    int qcount = 0;
    if (valid) {
        const float4 a = a4[i];
        const float4 b = b4[i];
        const int4  op = op4[i];
        float4 o;
        #pragma unroll
        for (int j = 0; j < 4; ++j) {
            const float aj = (&a.x)[j];
            const float bj = (&b.x)[j];
            const int  opj = (&op.x)[j];
            const float r0 = mod_step(aj, bj);        // a mod b, exact
            (&o.x)[j] = (opj == 0) ? r0 * wm : 0.0f;  // op1 slots overwritten in B
            const bool need = (opj == 1);
            const unsigned long long mask = __ballot(need);
            if (need) {
                const int pos = wbase + qcount +
                    (int)__popcll(mask & ((1ull << lane) - 1ull));
                qbr[pos] = make_float2(bj, r0);       // one ds_write_b64
                qs[pos]  = tid * 4 + j;
            }
            qcount += (int)__popcll(mask);            // wave-uniform (SGPR)
        }
        ((float4*)res)[tid] = o;                      // one ds_write_b128
    }

    // ---- phase B: dense centered-Euclid over the wave's own queue ----
    // (no barrier: producer and consumer are the same wave)
    for (int k = lane; k < qcount; k += 64) {
        const float2 br = qbr[wbase + k];
        const int  slot = qs[wbase + k];
        float x = br.x;
        float y = br.y;
        while (y > 0.0f) {
            const float q = floorf(fmaf(x, __builtin_amdgcn_rcpf(y), -0.5f));
            const float r = fmaf(-q, y, x);                  // exact, [0, 2y)
            const float c = fminf(fminf(r, fabsf(r - y)),    // v_min3_f32
                                  fmaf(2.0f, y, -r));
            x = y;
            y = c;
        }
        res[slot] = x * wg;
    }

    // ---- phase C: coalesced write-out (own wave's region only) ----
    if (valid) {
        out4[i] = ((const float4*)res)[tid];
    }
}

extern "C" void kernel_launch(void* const* d_in, const int* in_sizes, int n_in,
                              void* d_out, int out_size, void* d_ws, size_t ws_size,
                              hipStream_t stream) {
    const float* a   = (const float*)d_in[0];
    const float* b   = (const float*)d_in[1];
    const int*   op  = (const int*)d_in[2];
    const float* Wm  = (const float*)d_in[3];
    const float* Wg  = (const float*)d_in[4];
    float* out = (float*)d_out;

    const int n  = in_sizes[0];      // 8388608
    const int n4 = n >> 2;           // 2097152 float4 elements
    const int blocks = (n4 + TPB - 1) / TPB;   // 8192

    nt_kernel<<<blocks, TPB, 0, stream>>>(
        (const float4*)a, (const float4*)b, (const int4*)op, Wm, Wg,
        (float4*)out, n4);
}

// Round 7
// 26.757 us; speedup vs baseline: 1.2631x; 1.0586x over previous
//
#include <hip/hip_runtime.h>

// op 0: fmod(a,b) * W_mod ; op 1: gcd(int(a),int(b)) * W_gcd ; else 0.
// a,b integer-valued floats in [1, 1e6) -> exact in fp32.
//
// Phase A (exact plain mod, needed for op0's [0,b) representative):
//   q = floor(fma(x, rcp(y), -0.5)) is within +/-0.19 of x/y - 0.5
//   (rcp <=1 ulp, x < 2^20), so q in {k-1, k}; r = fma(-q, y, x) is an exact
//   integer in [0, 2y); one conditional subtract gives the exact mod.
//
// Phase B (gcd) uses the SIGNED NEAREST-QUOTIENT step:
//   q = rndne(x * rcp(y)); r = fma(-q, y, x); x = y; y = |r|
// |x*rcp(y) - x/y| <= 0.19  =>  |q - x/y| <= 0.69  =>  |r| <= 0.69*y,
// r exact (integer, |q*y| < 2^21 -> fma's single rounding is exact).
// gcd(y,|r|) == gcd(x,y); 0.69 contraction -> <= ~37 steps worst, ~7 avg.
// rintf() compiles to v_rndne_f32 (default RNE mode on gfx950); fabs folds
// into the consumer's input modifier. Loop body ~6 VALU ops.
//
// ISSUE-BOUND lessons: only instruction-count cuts pay (round 4's paired
// branchless loop regressed: 2*E[max128] > 2*E[max64] iterations). Phase B
// stays sequential early-exit, one item per lane per round.
//
// Each WAVE owns 256 elements (4/lane); gcd tasks are compacted into a
// wave-private LDS queue via ballot + prefix-popc + SGPR running count.
// No atomics, no __syncthreads (same-wave LDS ordering is guaranteed by the
// in-order DS pipeline). Queue payload (b, r0) packed as float2 -> b64 DS ops.

#define TPB 256

__device__ __forceinline__ float mod_step(float x, float y) {
    // precondition: y >= 1, x >= 0, both integer-valued, < 2^20
    float q = floorf(fmaf(x, __builtin_amdgcn_rcpf(y), -0.5f));
    float r = fmaf(-q, y, x);          // exact integer in [0, 2y)
    return (r >= y) ? r - y : r;
}

extern "C" __global__ void __launch_bounds__(256)
nt_kernel(const float4* __restrict__ a4, const float4* __restrict__ b4,
          const int4* __restrict__ op4, const float* __restrict__ Wm,
          const float* __restrict__ Wg, float4* __restrict__ out4, int n4)
{
    __shared__ __align__(16) float  res[1024];  // per-block results, 4/thread
    __shared__ __align__(8)  float2 qbr[1024];  // queue: (x0 = b, y0 = a mod b)
    __shared__ int    qs[1024];                 // queue: result slot

    const int tid   = threadIdx.x;
    const int lane  = tid & 63;
    const int wbase = (tid >> 6) << 8;          // 256 queue slots per wave

    const int i = blockIdx.x * TPB + tid;       // float4 index
    const bool valid = (i < n4);
    const float wm = Wm[0];
    const float wg = Wg[0];

    // ---- phase A: mod for everyone, wave-local gcd-task compaction ----
    int qcount = 0;
    if (valid) {
        const float4 a = a4[i];
        const float4 b = b4[i];
        const int4  op = op4[i];
        float4 o;
        #pragma unroll
        for (int j = 0; j < 4; ++j) {
            const float aj = (&a.x)[j];
            const float bj = (&b.x)[j];
            const int  opj = (&op.x)[j];
            const float r0 = mod_step(aj, bj);        // a mod b, exact
            (&o.x)[j] = (opj == 0) ? r0 * wm : 0.0f;  // op1 slots overwritten in B
            const bool need = (opj == 1);
            const unsigned long long mask = __ballot(need);
            if (need) {
                const int pos = wbase + qcount +
                    (int)__popcll(mask & ((1ull << lane) - 1ull));
                qbr[pos] = make_float2(bj, r0);       // one ds_write_b64
                qs[pos]  = tid * 4 + j;
            }
            qcount += (int)__popcll(mask);            // wave-uniform (SGPR)
        }
        ((float4*)res)[tid] = o;                      // one ds_write_b128
    }

    // ---- phase B: dense signed-nearest-quotient gcd over the wave's queue ----
    // (no barrier: producer and consumer are the same wave)
    for (int k = lane; k < qcount; k += 64) {
        const float2 br = qbr[wbase + k];
        const int  slot = qs[wbase + k];
        float x = br.x;                 // b  (>= 1)
        float y = br.y;                 // a mod b, in [0, b)
        while (y > 0.0f) {
            const float q = rintf(x * __builtin_amdgcn_rcpf(y));  // v_rndne_f32
            const float r = fmaf(-q, y, x);   // exact integer, |r| <= 0.69*y
            x = y;
            y = fabsf(r);
        }
        res[slot] = x * wg;
    }

    // ---- phase C: coalesced write-out (own wave's region only) ----
    if (valid) {
        out4[i] = ((const float4*)res)[tid];
    }
}

extern "C" void kernel_launch(void* const* d_in, const int* in_sizes, int n_in,
                              void* d_out, int out_size, void* d_ws, size_t ws_size,
                              hipStream_t stream) {
    const float* a   = (const float*)d_in[0];
    const float* b   = (const float*)d_in[1];
    const int*   op  = (const int*)d_in[2];
    const float* Wm  = (const float*)d_in[3];
    const float* Wg  = (const float*)d_in[4];
    float* out = (float*)d_out;

    const int n  = in_sizes[0];      // 8388608
    const int n4 = n >> 2;           // 2097152 float4 elements
    const int blocks = (n4 + TPB - 1) / TPB;   // 8192

    nt_kernel<<<blocks, TPB, 0, stream>>>(
        (const float4*)a, (const float4*)b, (const int4*)op, Wm, Wg,
        (float4*)out, n4);
}